// Round 5
// baseline (1165.471 us; speedup 1.0000x reference)
//
#include <hip/hip_runtime.h>
#include <hip/hip_bf16.h>

static constexpr int Bn = 8, Dn = 512, Hn = 64, Wn = 64, Kn = 1024;
static constexpr int HW = Hn * Wn;            // 4096
static constexpr int NPIX = Bn * HW;          // 32768
static constexpr size_t OFF_LOSS = (size_t)Bn * Dn * HW;          // 16777216
static constexpr size_t OFF_PROB = OFF_LOSS + 1;                   // 16777217
static constexpr size_t OFF_IDX  = OFF_PROB + (size_t)NPIX * Kn;   // 50331649
static constexpr size_t OFF_PPRB = OFF_IDX + NPIX;                 // 50364417

typedef __attribute__((ext_vector_type(8))) short short8v;
typedef __attribute__((ext_vector_type(4))) float f32x4;
typedef unsigned long long ull;

// workspace layout (bytes)
static constexpr size_t WS_CB2    = 0;        // 1024 f32
static constexpr size_t WS_XXZ    = 4096;     // 32768 f32
static constexpr size_t WS_WIDX   = 135168;   // 32768 i32
static constexpr size_t WS_NFLAG  = 266240;   // 1 i32
static constexpr size_t WS_FLAGS  = 267264;   // 32768 i32 (packed p<<10|k)
static constexpr size_t WS_REFMIN = 398336;   // 32768 u64
static constexpr size_t WS_PART   = 660480;   // 4096 f32
static constexpr size_t WS_CBBF   = 676864;   // 1024*512 bf16 (1 MB)

#define MARGIN 1.5e-3f

__device__ inline unsigned short f2bf(float x) {
  unsigned u = __float_as_uint(x);
  u += 0x7fffu + ((u >> 16) & 1u);  // RNE
  return (unsigned short)(u >> 16);
}
__device__ inline float bf2f(unsigned short h) {
  return __uint_as_float(((unsigned)h) << 16);
}

// ---- numpy pairwise-sum replica for n=512 f32 row of squares ----
__device__ float np_pairwise_sq512(const float* __restrict__ base, int stride) {
  float B[4];
#pragma unroll
  for (int blk = 0; blk < 4; blk++) {
    const float* a = base + (size_t)blk * 128 * stride;
    float r[8][4];
#pragma unroll
    for (int k = 0; k < 8; k++)
#pragma unroll
      for (int j = 0; j < 4; j++) {
        float x = a[(size_t)(4 * k + j) * stride];
        r[k][j] = __fmul_rn(x, x);
      }
#pragma unroll
    for (int i = 32; i < 128; i += 32)
#pragma unroll
      for (int k = 0; k < 8; k++)
#pragma unroll
        for (int j = 0; j < 4; j++) {
          float x = a[(size_t)(i + 4 * k + j) * stride];
          r[k][j] = __fadd_rn(r[k][j], __fmul_rn(x, x));
        }
    float L[4];
#pragma unroll
    for (int j = 0; j < 4; j++) {
      float t01 = __fadd_rn(r[0][j], r[1][j]);
      float t23 = __fadd_rn(r[2][j], r[3][j]);
      float t45 = __fadd_rn(r[4][j], r[5][j]);
      float t67 = __fadd_rn(r[6][j], r[7][j]);
      L[j] = __fadd_rn(__fadd_rn(t01, t23), __fadd_rn(t45, t67));
    }
    B[blk] = __fadd_rn(__fadd_rn(L[0], L[1]), __fadd_rn(L[2], L[3]));
  }
  return __fadd_rn(__fadd_rn(B[0], B[1]), __fadd_rn(B[2], B[3]));
}

// ---------------- K0: cvt CB->bf16 + np-replica norms + inits ----------------
// grid 1024 x 256
__global__ __launch_bounds__(256) void k_init(const float* __restrict__ Z,
                                              const float* __restrict__ CB,
                                              unsigned short* __restrict__ CBbf,
                                              float* __restrict__ xxZ,
                                              float* __restrict__ cb2,
                                              ull* __restrict__ refmin,
                                              int* __restrict__ nflag) {
  int gid = blockIdx.x * 256 + threadIdx.x;
  {
    float2 f = *(const float2*)(CB + (size_t)gid * 2);
    union { __hip_bfloat162 h; unsigned u; } cv;
    cv.h = __float22bfloat162_rn(f);
    ((unsigned*)CBbf)[gid] = cv.u;
  }
  if (gid < NPIX) {
    int b = gid >> 12, hw = gid & 4095;
    xxZ[gid] = np_pairwise_sq512(Z + (size_t)b * Dn * HW + hw, HW);
    refmin[gid] = ~0ull;
  } else if (gid < NPIX + Kn) {
    int k = gid - NPIX;
    cb2[k] = np_pairwise_sq512(CB + (size_t)k * Dn, 1);
  }
  if (gid == 0) *nflag = 0;
}

// ---------------- K1: fused GEMM + softmax + argmin/flag ----------------
// grid (1024, 2), block 256 (4 waves). Block: 32 p-rows x full K=1024.
// Wave w owns cols [nc*256 + w*64, +64) for nc=0..3 (column-chunked acc).
__global__ __launch_bounds__(256, 3) void k_fused(const float* __restrict__ Z,
                                                  const float* __restrict__ ZP,
                                                  const unsigned short* __restrict__ CBbf,
                                                  const float* __restrict__ cb2,
                                                  float* __restrict__ out,
                                                  int* __restrict__ widx,
                                                  int* __restrict__ nflag,
                                                  int* __restrict__ flags) {
  __shared__ __align__(16) unsigned short Abf[32 * 512];  // 32KB, XOR-swizzled
  __shared__ float c2s[1024];
  __shared__ float redv[4][32];
  __shared__ int   redi[4][32];
  __shared__ float reds[4][32];
  __shared__ int   redc[4][32];
  __shared__ float rowmin_s[32];
  __shared__ int   rowidx_s[32];
  __shared__ float rowinv_s[32];
  __shared__ int   rowcnt_s[32];
  __shared__ int pcnt, pbase;
  __shared__ int pbuf[512];

  const int py = blockIdx.x;
  const int zz = blockIdx.y;
  const int p0 = py * 32;
  const float* A = zz ? ZP : Z;
  float* S = out + (zz ? OFF_PPRB : OFF_PROB);
  const float* Ab = A + (size_t)(p0 >> 12) * (Dn * HW) + (p0 & 4095);
  const int tid = threadIdx.x;
  const int lane = tid & 63, w = tid >> 6;
  const int fr = lane & 15, fg = lane >> 4;
  if (tid == 0) pcnt = 0;

#pragma unroll
  for (int i = 0; i < 4; i++) c2s[tid + i * 256] = cb2[tid + i * 256];

  // stage A (32 rows x 512 c) -> LDS bf16 with XOR swizzle
  {
    const int sp = tid & 31;         // p row
    const int sg = tid >> 5;         // 8 groups x 64 c
    const float* Ac = Ab + sp;
#pragma unroll
    for (int j = 0; j < 8; j++) {
      int cb0 = sg * 64 + j * 8;
      float v[8];
#pragma unroll
      for (int q = 0; q < 8; q++) v[q] = Ac[(size_t)(cb0 + q) * HW];
      uint4 ua;
      union { __hip_bfloat162 h; unsigned u; } t0, t1, t2, t3;
      t0.h = __float22bfloat162_rn(make_float2(v[0], v[1]));
      t1.h = __float22bfloat162_rn(make_float2(v[2], v[3]));
      t2.h = __float22bfloat162_rn(make_float2(v[4], v[5]));
      t3.h = __float22bfloat162_rn(make_float2(v[6], v[7]));
      ua.x = t0.u; ua.y = t1.u; ua.z = t2.u; ua.w = t3.u;
      int bo = ((sp * 512 + cb0) * 2) ^ ((sp & 7) << 4);
      *(uint4*)((char*)Abf + bo) = ua;
    }
  }
  __syncthreads();

  // GEMM, column-chunked; s packed to bf16 pairs
  unsigned spack[64];
#pragma unroll
  for (int nc = 0; nc < 4; nc++) {
    const int kbase = nc * 256 + w * 64;
    f32x4 acc[2][4] = {};
#pragma unroll
    for (int c0 = 0; c0 < 512; c0 += 32) {
      short8v af[2];
#pragma unroll
      for (int m = 0; m < 2; m++) {
        int row = m * 16 + fr;
        int bo = ((row * 512 + c0 + fg * 8) * 2) ^ ((row & 7) << 4);
        af[m] = *(const short8v*)((const char*)Abf + bo);
      }
      short8v bfv[4];
#pragma unroll
      for (int n = 0; n < 4; n++)
        bfv[n] = *(const short8v*)(CBbf + (size_t)(kbase + n * 16 + fr) * 512 + c0 + fg * 8);
#pragma unroll
      for (int m = 0; m < 2; m++)
#pragma unroll
        for (int n = 0; n < 4; n++)
          acc[m][n] = __builtin_amdgcn_mfma_f32_16x16x32_bf16(af[m], bfv[n], acc[m][n], 0, 0, 0);
    }
    // s = cb2 - 2*m (xx cancels), pack to bf16 pairs (n, n+1)
#pragma unroll
    for (int m = 0; m < 2; m++)
#pragma unroll
      for (int r = 0; r < 4; r++)
#pragma unroll
        for (int h = 0; h < 2; h++) {
          float s0 = __fsub_rn(c2s[kbase + (h * 2) * 16 + fr], __fmul_rn(2.0f, acc[m][h * 2][r]));
          float s1 = __fsub_rn(c2s[kbase + (h * 2 + 1) * 16 + fr], __fmul_rn(2.0f, acc[m][h * 2 + 1][r]));
          spack[nc * 16 + (m * 4 + r) * 2 + h] = (unsigned)f2bf(s0) | ((unsigned)f2bf(s1) << 16);
        }
  }

  // phase 1: per-row lexicographic (val, idx) min over bf16 s
  float bv[8]; int bi[8];
#pragma unroll
  for (int e = 0; e < 8; e++) { bv[e] = 1e30f; bi[e] = 0x7fffffff; }
#pragma unroll
  for (int nc = 0; nc < 4; nc++)
#pragma unroll
    for (int e = 0; e < 8; e++)
#pragma unroll
      for (int h = 0; h < 2; h++) {
        unsigned pk = spack[nc * 16 + e * 2 + h];
        float s0 = bf2f((unsigned short)pk), s1 = bf2f((unsigned short)(pk >> 16));
        int c0i = nc * 256 + w * 64 + h * 32 + fr;
        if (s0 < bv[e] || (s0 == bv[e] && c0i < bi[e])) { bv[e] = s0; bi[e] = c0i; }
        int c1i = c0i + 16;
        if (s1 < bv[e] || (s1 == bv[e] && c1i < bi[e])) { bv[e] = s1; bi[e] = c1i; }
      }
#pragma unroll
  for (int e = 0; e < 8; e++) {
    float v = bv[e]; int i = bi[e];
#pragma unroll
    for (int d = 1; d < 16; d <<= 1) {
      float ov = __shfl_xor(v, d, 64);
      int oi = __shfl_xor(i, d, 64);
      if (ov < v || (ov == v && oi < i)) { v = ov; i = oi; }
    }
    if (fr == 0) {
      int row = (e >> 2) * 16 + fg * 4 + (e & 3);
      redv[w][row] = v; redi[w][row] = i;
    }
  }
  __syncthreads();
  if (tid < 32) {
    float v = redv[0][tid]; int i = redi[0][tid];
    for (int ww = 1; ww < 4; ww++) {
      float ov = redv[ww][tid]; int oi = redi[ww][tid];
      if (ov < v || (ov == v && oi < i)) { v = ov; i = oi; }
    }
    rowmin_s[tid] = v; rowidx_s[tid] = i;
  }
  __syncthreads();

  // phase 2: exp-sum (offset-free) + margin count
  float sum[8]; int cnt[8]; float rmv[8];
#pragma unroll
  for (int e = 0; e < 8; e++) {
    sum[e] = 0.f; cnt[e] = 0;
    rmv[e] = rowmin_s[(e >> 2) * 16 + fg * 4 + (e & 3)] + MARGIN;
  }
#pragma unroll
  for (int nc = 0; nc < 4; nc++)
#pragma unroll
    for (int e = 0; e < 8; e++)
#pragma unroll
      for (int h = 0; h < 2; h++) {
        unsigned pk = spack[nc * 16 + e * 2 + h];
        float s0 = bf2f((unsigned short)pk), s1 = bf2f((unsigned short)(pk >> 16));
        sum[e] += __expf(-s0) + __expf(-s1);
        cnt[e] += (s0 <= rmv[e]) + (s1 <= rmv[e]);
      }
#pragma unroll
  for (int e = 0; e < 8; e++) {
    float sm = sum[e]; int ct = cnt[e];
#pragma unroll
    for (int d = 1; d < 16; d <<= 1) {
      sm += __shfl_xor(sm, d, 64);
      ct += __shfl_xor(ct, d, 64);
    }
    if (fr == 0) {
      int row = (e >> 2) * 16 + fg * 4 + (e & 3);
      reds[w][row] = sm; redc[w][row] = ct;
    }
  }
  __syncthreads();
  if (tid < 32) {
    float sm = 0.f; int ct = 0;
    for (int ww = 0; ww < 4; ww++) { sm += reds[ww][tid]; ct += redc[ww][tid]; }
    rowinv_s[tid] = 1.0f / sm;
    rowcnt_s[tid] = ct;
    if (zz == 0 && ct == 1) {
      widx[p0 + tid] = rowidx_s[tid];
      out[OFF_IDX + p0 + tid] = (float)rowidx_s[tid];
    }
  }
  __syncthreads();

  // phase 3: probs + candidate flags
#pragma unroll
  for (int e = 0; e < 8; e++) {
    const int row = (e >> 2) * 16 + fg * 4 + (e & 3);
    const float inv = rowinv_s[row];
    const float rm = rowmin_s[row] + MARGIN;
    const bool multi = rowcnt_s[row] > 1;
    float* Sp = S + (size_t)(p0 + row) * Kn + fr;
#pragma unroll
    for (int nc = 0; nc < 4; nc++)
#pragma unroll
      for (int h = 0; h < 2; h++) {
        unsigned pk = spack[nc * 16 + e * 2 + h];
        float s0 = bf2f((unsigned short)pk), s1 = bf2f((unsigned short)(pk >> 16));
        int c0i = nc * 256 + w * 64 + h * 32;
        Sp[c0i] = __expf(-s0) * inv;
        Sp[c0i + 16] = __expf(-s1) * inv;
        if (zz == 0 && multi) {
          if (s0 <= rm) {
            int sl = atomicAdd(&pcnt, 1);
            if (sl < 512) pbuf[sl] = ((p0 + row) << 10) | (c0i + fr);
          }
          if (s1 <= rm) {
            int sl = atomicAdd(&pcnt, 1);
            if (sl < 512) pbuf[sl] = ((p0 + row) << 10) | (c0i + 16 + fr);
          }
        }
      }
  }
  __syncthreads();
  if (zz == 0) {
    if (tid == 0) pbase = atomicAdd(nflag, min(pcnt, 512));
    __syncthreads();
    int npairs = min(pcnt, 512);
    for (int i = tid; i < npairs; i += 256) flags[pbase + i] = pbuf[i];
  }
}

// ---------------- K2: exact seq-fma recompute per flagged (p,k) pair ----------------
__global__ __launch_bounds__(256) void k_refine(const float* __restrict__ Z,
                                                const float* __restrict__ CB,
                                                const float* __restrict__ cb2,
                                                const float* __restrict__ xxZ,
                                                const int* __restrict__ flags,
                                                const int* __restrict__ nflag,
                                                ull* __restrict__ refmin) {
  const int np = min(*nflag, NPIX);
  for (int i = blockIdx.x * 256 + threadIdx.x; i < np; i += 256 * 256) {
    int pk = flags[i];
    int p = pk >> 10, k = pk & 1023;
    const float* zr = Z + (size_t)(p >> 12) * (Dn * HW) + (p & 4095);
    const float* cr = CB + (size_t)k * Dn;
    float m = 0.f;
    for (int c = 0; c < Dn; c++)
      m = fmaf(zr[(size_t)c * HW], cr[c], m);   // sequential, np-matching
    float d = __fsub_rn(__fadd_rn(xxZ[p], cb2[k]), __fmul_rn(2.0f, m));
    ull key = ((ull)__float_as_uint(d) << 32) | (unsigned)k;  // d>0; ties -> lowest k
    atomicMin(refmin + p, key);
  }
}

// ---------------- K3: write back refined argmin ----------------
__global__ __launch_bounds__(256) void k_refidx(const int* __restrict__ flags,
                                                const int* __restrict__ nflag,
                                                const ull* __restrict__ refmin,
                                                int* __restrict__ widx,
                                                float* __restrict__ out) {
  const int np = min(*nflag, NPIX);
  for (int i = blockIdx.x * 256 + threadIdx.x; i < np; i += 64 * 256) {
    int p = flags[i] >> 10;
    int k = (int)(refmin[p] & 0x3ffu);
    widx[p] = k;
    out[OFF_IDX + p] = (float)k;
  }
}

// ---------------- K4: z_q gather + squared-error partials ----------------
__global__ __launch_bounds__(256) void k_zqloss(const float* __restrict__ Z,
                                                const float* __restrict__ CB,
                                                const int* __restrict__ widx,
                                                float* __restrict__ out,
                                                float* __restrict__ partial) {
  __shared__ float red[256];
  const int t = threadIdx.x;
  float ls = 0.f;
  const size_t base = (size_t)blockIdx.x * 4096;
#pragma unroll
  for (int i = 0; i < 16; i++) {
    size_t e = base + (size_t)i * 256 + t;
    int hw = (int)(e & 4095);
    int c = (int)((e >> 12) & 511);
    int bb = (int)(e >> 21);
    int p = (bb << 12) | hw;
    float zv = Z[e];
    float qv = CB[(size_t)widx[p] * Dn + c];
    out[e] = qv;
    float d = zv - qv;
    ls = fmaf(d, d, ls);
  }
  red[t] = ls;
  __syncthreads();
  for (int s = 128; s > 0; s >>= 1) {
    if (t < s) red[t] += red[t + s];
    __syncthreads();
  }
  if (t == 0) partial[blockIdx.x] = red[0];
}

// ---------------- K5: finalize q_loss ----------------
__global__ __launch_bounds__(256) void k_loss(const float* __restrict__ partial,
                                              float* __restrict__ out) {
  __shared__ float red[256];
  const int t = threadIdx.x;
  float s = 0.f;
  for (int i = t; i < 4096; i += 256) s += partial[i];
  red[t] = s;
  __syncthreads();
  for (int k = 128; k > 0; k >>= 1) {
    if (t < k) red[t] += red[t + k];
    __syncthreads();
  }
  if (t == 0) out[OFF_LOSS] = red[0] * (1.25f / 16777216.0f);
}

extern "C" void kernel_launch(void* const* d_in, const int* in_sizes, int n_in,
                              void* d_out, int out_size, void* d_ws, size_t ws_size,
                              hipStream_t stream) {
  const float* Z = (const float*)d_in[0];
  const float* ZP = (const float*)d_in[1];
  const float* CB = (const float*)d_in[2];
  float* out = (float*)d_out;
  char* ws = (char*)d_ws;
  float* cb2 = (float*)(ws + WS_CB2);
  float* xxZ = (float*)(ws + WS_XXZ);
  int* widx = (int*)(ws + WS_WIDX);
  int* nflag = (int*)(ws + WS_NFLAG);
  int* flags = (int*)(ws + WS_FLAGS);
  ull* refmin = (ull*)(ws + WS_REFMIN);
  float* partial = (float*)(ws + WS_PART);
  unsigned short* CBbf = (unsigned short*)(ws + WS_CBBF);

  k_init<<<dim3(1024), 256, 0, stream>>>(Z, CB, CBbf, xxZ, cb2, refmin, nflag);
  k_fused<<<dim3(1024, 2), 256, 0, stream>>>(Z, ZP, CBbf, cb2, out, widx, nflag, flags);
  k_refine<<<dim3(256), 256, 0, stream>>>(Z, CB, cb2, xxZ, flags, nflag, refmin);
  k_refidx<<<dim3(64), 256, 0, stream>>>(flags, nflag, refmin, widx, out);
  k_zqloss<<<dim3(4096), 256, 0, stream>>>(Z, CB, widx, out, partial);
  k_loss<<<dim3(1), 256, 0, stream>>>(partial, out);
}

// Round 6
// 544.882 us; speedup vs baseline: 2.1389x; 2.1389x over previous
//
#include <hip/hip_runtime.h>
#include <hip/hip_bf16.h>

static constexpr int Bn = 8, Dn = 512, Hn = 64, Wn = 64, Kn = 1024;
static constexpr int HW = Hn * Wn;            // 4096
static constexpr int NPIX = Bn * HW;          // 32768
static constexpr size_t OFF_LOSS = (size_t)Bn * Dn * HW;          // 16777216
static constexpr size_t OFF_PROB = OFF_LOSS + 1;                   // 16777217
static constexpr size_t OFF_IDX  = OFF_PROB + (size_t)NPIX * Kn;   // 50331649
static constexpr size_t OFF_PPRB = OFF_IDX + NPIX;                 // 50364417

typedef __attribute__((ext_vector_type(8))) short short8v;
typedef __attribute__((ext_vector_type(4))) float f32x4;
typedef unsigned long long ull;

// workspace layout (bytes)
static constexpr size_t WS_CB2    = 0;        // 1024 f32
static constexpr size_t WS_XXZ    = 4096;     // 32768 f32
static constexpr size_t WS_WIDX   = 135168;   // 32768 i32
static constexpr size_t WS_NFLAG  = 266240;   // 1 i32
static constexpr size_t WS_FLAGS  = 267264;   // 32768 i32 (packed p<<10|k)
static constexpr size_t WS_REFMIN = 398336;   // 32768 u64
static constexpr size_t WS_PART   = 660480;   // 4096 f32
static constexpr size_t WS_CBBF   = 676864;   // 1024*512 bf16 (1 MB)

#define MARGIN 1e-3f

// ---- numpy pairwise-sum replica for n=512 f32 row of squares ----
__device__ float np_pairwise_sq512(const float* __restrict__ base, int stride) {
  float B[4];
#pragma unroll
  for (int blk = 0; blk < 4; blk++) {
    const float* a = base + (size_t)blk * 128 * stride;
    float r[8][4];
#pragma unroll
    for (int k = 0; k < 8; k++)
#pragma unroll
      for (int j = 0; j < 4; j++) {
        float x = a[(size_t)(4 * k + j) * stride];
        r[k][j] = __fmul_rn(x, x);
      }
#pragma unroll
    for (int i = 32; i < 128; i += 32)
#pragma unroll
      for (int k = 0; k < 8; k++)
#pragma unroll
        for (int j = 0; j < 4; j++) {
          float x = a[(size_t)(i + 4 * k + j) * stride];
          r[k][j] = __fadd_rn(r[k][j], __fmul_rn(x, x));
        }
    float L[4];
#pragma unroll
    for (int j = 0; j < 4; j++) {
      float t01 = __fadd_rn(r[0][j], r[1][j]);
      float t23 = __fadd_rn(r[2][j], r[3][j]);
      float t45 = __fadd_rn(r[4][j], r[5][j]);
      float t67 = __fadd_rn(r[6][j], r[7][j]);
      L[j] = __fadd_rn(__fadd_rn(t01, t23), __fadd_rn(t45, t67));
    }
    B[blk] = __fadd_rn(__fadd_rn(L[0], L[1]), __fadd_rn(L[2], L[3]));
  }
  return __fadd_rn(__fadd_rn(B[0], B[1]), __fadd_rn(B[2], B[3]));
}

// ---------------- K0: cvt CB->bf16 + np-replica norms + inits ----------------
__global__ __launch_bounds__(256) void k_init(const float* __restrict__ Z,
                                              const float* __restrict__ CB,
                                              unsigned short* __restrict__ CBbf,
                                              float* __restrict__ xxZ,
                                              float* __restrict__ cb2,
                                              ull* __restrict__ refmin,
                                              int* __restrict__ nflag) {
  int gid = blockIdx.x * 256 + threadIdx.x;
  {
    float2 f = *(const float2*)(CB + (size_t)gid * 2);
    union { __hip_bfloat162 h; unsigned u; } cv;
    cv.h = __float22bfloat162_rn(f);
    ((unsigned*)CBbf)[gid] = cv.u;
  }
  if (gid < NPIX) {
    int b = gid >> 12, hw = gid & 4095;
    xxZ[gid] = np_pairwise_sq512(Z + (size_t)b * Dn * HW + hw, HW);
    refmin[gid] = ~0ull;
  } else if (gid < NPIX + Kn) {
    int k = gid - NPIX;
    cb2[k] = np_pairwise_sq512(CB + (size_t)k * Dn, 1);
  }
  if (gid == 0) *nflag = 0;
}

// ---------------- K1: fused GEMM (z & z_pos) + softmax + argmin/flag ----------------
// grid 1024, block 512 (8 waves). Block: 32 p-rows x full K=1024, both matrices.
// Wave w owns cols [w*128, w*128+128).
__global__ __launch_bounds__(512, 2) void k_fused(const float* __restrict__ Z,
                                                  const float* __restrict__ ZP,
                                                  const unsigned short* __restrict__ CBbf,
                                                  const float* __restrict__ cb2,
                                                  float* __restrict__ out,
                                                  int* __restrict__ widx,
                                                  int* __restrict__ nflag,
                                                  int* __restrict__ flags) {
  __shared__ __align__(16) unsigned short Abf[2 * 32 * 512];  // 64KB, XOR-swizzled
  __shared__ float redv[8][32];
  __shared__ int   redi[8][32];
  __shared__ float reds[8][32];
  __shared__ int   redc[8][32];
  __shared__ float rowmin_s[32];
  __shared__ int   rowidx_s[32];
  __shared__ float rowinv_s[32];
  __shared__ int   rowcnt_s[32];
  __shared__ int pcnt, pbase;
  __shared__ int pbuf[512];

  const int py = blockIdx.x;
  const int p0 = py * 32;
  const int tid = threadIdx.x;
  const int lane = tid & 63, w = tid >> 6;
  const int fr = lane & 15, fg = lane >> 4;
  if (tid == 0) pcnt = 0;

  // ---- stage A (both mats, 32 rows x 512 c) -> LDS bf16, XOR swizzle ----
  {
    const int sp = tid & 31;          // p row
    const int sg = tid >> 5;          // 16 groups x 32 c
    const size_t abase = (size_t)(p0 >> 12) * (Dn * HW) + (p0 & 4095) + sp;
#pragma unroll
    for (int mat = 0; mat < 2; mat++) {
      const float* Ac = (mat ? ZP : Z) + abase;
#pragma unroll
      for (int j = 0; j < 4; j++) {
        int cb0 = sg * 32 + j * 8;
        float v[8];
#pragma unroll
        for (int q = 0; q < 8; q++) v[q] = Ac[(size_t)(cb0 + q) * HW];
        uint4 ua;
        union { __hip_bfloat162 h; unsigned u; } t0, t1, t2, t3;
        t0.h = __float22bfloat162_rn(make_float2(v[0], v[1]));
        t1.h = __float22bfloat162_rn(make_float2(v[2], v[3]));
        t2.h = __float22bfloat162_rn(make_float2(v[4], v[5]));
        t3.h = __float22bfloat162_rn(make_float2(v[6], v[7]));
        ua.x = t0.u; ua.y = t1.u; ua.z = t2.u; ua.w = t3.u;
        int bo = ((sp * 512 + cb0) * 2) ^ ((sp & 7) << 4);
        *(uint4*)((char*)Abf + mat * 32768 + bo) = ua;
      }
    }
  }
  __syncthreads();

  // ---- GEMM: one pass over B serves both matrices ----
  const int kbase = w * 128;
  f32x4 acc[2][2][8] = {};   // [mat][m][n]
#pragma unroll
  for (int c0 = 0; c0 < 512; c0 += 32) {
    short8v bfv[8];
#pragma unroll
    for (int n = 0; n < 8; n++)
      bfv[n] = *(const short8v*)(CBbf + (size_t)(kbase + n * 16 + fr) * 512 + c0 + fg * 8);
    short8v af[2][2];
#pragma unroll
    for (int mat = 0; mat < 2; mat++)
#pragma unroll
      for (int m = 0; m < 2; m++) {
        int row = m * 16 + fr;
        int bo = ((row * 512 + c0 + fg * 8) * 2) ^ ((row & 7) << 4);
        af[mat][m] = *(const short8v*)((const char*)Abf + mat * 32768 + bo);
      }
#pragma unroll
    for (int mat = 0; mat < 2; mat++)
#pragma unroll
      for (int m = 0; m < 2; m++)
#pragma unroll
        for (int n = 0; n < 8; n++)
          acc[mat][m][n] = __builtin_amdgcn_mfma_f32_16x16x32_bf16(af[mat][m], bfv[n], acc[mat][m][n], 0, 0, 0);
  }

  float c2[8];
#pragma unroll
  for (int n = 0; n < 8; n++) c2[n] = cb2[kbase + n * 16 + fr];

  // ---- epilogue per matrix (round-4 proven path) ----
#pragma unroll
  for (int mat = 0; mat < 2; mat++) {
    const bool isZ = (mat == 0);
    float* S = out + (isZ ? OFF_PROB : OFF_PPRB);

    // s = cb2[k] - 2*m (xx cancels in softmax/argmin; exact path in refine)
#pragma unroll
    for (int m = 0; m < 2; m++)
#pragma unroll
      for (int n = 0; n < 8; n++)
#pragma unroll
        for (int r = 0; r < 4; r++)
          acc[mat][m][n][r] = __fsub_rn(c2[n], __fmul_rn(2.0f, acc[mat][m][n][r]));

    __syncthreads();  // smem reuse boundary (mat0 -> mat1)

    // phase 1: lexicographic (val, idx) row-min
#pragma unroll
    for (int m = 0; m < 2; m++)
#pragma unroll
      for (int r = 0; r < 4; r++) {
        float bv = acc[mat][m][0][r];
        int bi = kbase + fr;
#pragma unroll
        for (int n = 1; n < 8; n++) {
          float x = acc[mat][m][n][r];
          int xi = kbase + n * 16 + fr;
          if (x < bv || (x == bv && xi < bi)) { bv = x; bi = xi; }
        }
#pragma unroll
        for (int d = 1; d < 16; d <<= 1) {
          float ov = __shfl_xor(bv, d, 64);
          int oi = __shfl_xor(bi, d, 64);
          if (ov < bv || (ov == bv && oi < bi)) { bv = ov; bi = oi; }
        }
        if (fr == 0) {
          int row = m * 16 + fg * 4 + r;
          redv[w][row] = bv; redi[w][row] = bi;
        }
      }
    __syncthreads();
    if (tid < 32) {
      float bv = redv[0][tid]; int bi = redi[0][tid];
      for (int ww = 1; ww < 8; ww++) {
        float ov = redv[ww][tid]; int oi = redi[ww][tid];
        if (ov < bv || (ov == bv && oi < bi)) { bv = ov; bi = oi; }
      }
      rowmin_s[tid] = bv; rowidx_s[tid] = bi;
    }
    __syncthreads();

    // phase 2: exp-sum + margin count
#pragma unroll
    for (int m = 0; m < 2; m++)
#pragma unroll
      for (int r = 0; r < 4; r++) {
        const int row = m * 16 + fg * 4 + r;
        const float rm = rowmin_s[row];
        float sum = 0.f; int cnt = 0;
#pragma unroll
        for (int n = 0; n < 8; n++) {
          float s = acc[mat][m][n][r];
          sum += __expf(rm - s);
          cnt += (s <= rm + MARGIN) ? 1 : 0;
        }
#pragma unroll
        for (int d = 1; d < 16; d <<= 1) {
          sum += __shfl_xor(sum, d, 64);
          cnt += __shfl_xor(cnt, d, 64);
        }
        if (fr == 0) { reds[w][row] = sum; redc[w][row] = cnt; }
      }
    __syncthreads();
    if (tid < 32) {
      float sm = 0.f; int ct = 0;
      for (int ww = 0; ww < 8; ww++) { sm += reds[ww][tid]; ct += redc[ww][tid]; }
      rowinv_s[tid] = 1.0f / sm;
      rowcnt_s[tid] = ct;
      if (isZ && ct == 1) {
        widx[p0 + tid] = rowidx_s[tid];
        out[OFF_IDX + p0 + tid] = (float)rowidx_s[tid];
      }
    }
    __syncthreads();

    // phase 3: probs + candidate flags
#pragma unroll
    for (int m = 0; m < 2; m++)
#pragma unroll
      for (int r = 0; r < 4; r++) {
        const int row = m * 16 + fg * 4 + r;
        const float rm = rowmin_s[row];
        const float inv = rowinv_s[row];
        const bool multi = (rowcnt_s[row] > 1);
        float* Sp = S + (size_t)(p0 + row) * Kn + kbase + fr;
#pragma unroll
        for (int n = 0; n < 8; n++) {
          float s = acc[mat][m][n][r];
          Sp[n * 16] = __expf(rm - s) * inv;
          if (isZ && multi && s <= rm + MARGIN) {
            int slot = atomicAdd(&pcnt, 1);
            if (slot < 512) pbuf[slot] = ((p0 + row) << 10) | (kbase + n * 16 + fr);
          }
        }
      }
    if (isZ) {
      __syncthreads();
      if (tid == 0) pbase = atomicAdd(nflag, min(pcnt, 512));
      __syncthreads();
      int npairs = min(pcnt, 512);
      if (tid < npairs) flags[pbase + tid] = pbuf[tid];
    }
  }
}

// ---------------- K2: exact seq-fma recompute per flagged (p,k) pair ----------------
__global__ __launch_bounds__(256) void k_refine(const float* __restrict__ Z,
                                                const float* __restrict__ CB,
                                                const float* __restrict__ cb2,
                                                const float* __restrict__ xxZ,
                                                const int* __restrict__ flags,
                                                const int* __restrict__ nflag,
                                                ull* __restrict__ refmin) {
  const int np = min(*nflag, NPIX);
  for (int i = blockIdx.x * 256 + threadIdx.x; i < np; i += 256 * 256) {
    int pk = flags[i];
    int p = pk >> 10, k = pk & 1023;
    const float* zr = Z + (size_t)(p >> 12) * (Dn * HW) + (p & 4095);
    const float* cr = CB + (size_t)k * Dn;
    float m = 0.f;
    for (int c = 0; c < Dn; c++)
      m = fmaf(zr[(size_t)c * HW], cr[c], m);   // sequential, np-matching
    float d = __fsub_rn(__fadd_rn(xxZ[p], cb2[k]), __fmul_rn(2.0f, m));
    ull key = ((ull)__float_as_uint(d) << 32) | (unsigned)k;  // d>0; ties -> lowest k
    atomicMin(refmin + p, key);
  }
}

// ---------------- K3: write back refined argmin ----------------
__global__ __launch_bounds__(256) void k_refidx(const int* __restrict__ flags,
                                                const int* __restrict__ nflag,
                                                const ull* __restrict__ refmin,
                                                int* __restrict__ widx,
                                                float* __restrict__ out) {
  const int np = min(*nflag, NPIX);
  for (int i = blockIdx.x * 256 + threadIdx.x; i < np; i += 64 * 256) {
    int p = flags[i] >> 10;
    int k = (int)(refmin[p] & 0x3ffu);
    widx[p] = k;
    out[OFF_IDX + p] = (float)k;
  }
}

// ---------------- K4: z_q gather + squared-error partials ----------------
__global__ __launch_bounds__(256) void k_zqloss(const float* __restrict__ Z,
                                                const float* __restrict__ CB,
                                                const int* __restrict__ widx,
                                                float* __restrict__ out,
                                                float* __restrict__ partial) {
  __shared__ float red[256];
  const int t = threadIdx.x;
  float ls = 0.f;
  const size_t base = (size_t)blockIdx.x * 4096;
#pragma unroll
  for (int i = 0; i < 16; i++) {
    size_t e = base + (size_t)i * 256 + t;
    int hw = (int)(e & 4095);
    int c = (int)((e >> 12) & 511);
    int bb = (int)(e >> 21);
    int p = (bb << 12) | hw;
    float zv = Z[e];
    float qv = CB[(size_t)widx[p] * Dn + c];
    out[e] = qv;
    float d = zv - qv;
    ls = fmaf(d, d, ls);
  }
  red[t] = ls;
  __syncthreads();
  for (int s = 128; s > 0; s >>= 1) {
    if (t < s) red[t] += red[t + s];
    __syncthreads();
  }
  if (t == 0) partial[blockIdx.x] = red[0];
}

// ---------------- K5: finalize q_loss ----------------
__global__ __launch_bounds__(256) void k_loss(const float* __restrict__ partial,
                                              float* __restrict__ out) {
  __shared__ float red[256];
  const int t = threadIdx.x;
  float s = 0.f;
  for (int i = t; i < 4096; i += 256) s += partial[i];
  __syncthreads();
  red[t] = s;
  __syncthreads();
  for (int k = 128; k > 0; k >>= 1) {
    if (t < k) red[t] += red[t + k];
    __syncthreads();
  }
  if (t == 0) out[OFF_LOSS] = red[0] * (1.25f / 16777216.0f);
}

extern "C" void kernel_launch(void* const* d_in, const int* in_sizes, int n_in,
                              void* d_out, int out_size, void* d_ws, size_t ws_size,
                              hipStream_t stream) {
  const float* Z = (const float*)d_in[0];
  const float* ZP = (const float*)d_in[1];
  const float* CB = (const float*)d_in[2];
  float* out = (float*)d_out;
  char* ws = (char*)d_ws;
  float* cb2 = (float*)(ws + WS_CB2);
  float* xxZ = (float*)(ws + WS_XXZ);
  int* widx = (int*)(ws + WS_WIDX);
  int* nflag = (int*)(ws + WS_NFLAG);
  int* flags = (int*)(ws + WS_FLAGS);
  ull* refmin = (ull*)(ws + WS_REFMIN);
  float* partial = (float*)(ws + WS_PART);
  unsigned short* CBbf = (unsigned short*)(ws + WS_CBBF);

  k_init<<<dim3(1024), 256, 0, stream>>>(Z, CB, CBbf, xxZ, cb2, refmin, nflag);
  k_fused<<<dim3(1024), 512, 0, stream>>>(Z, ZP, CBbf, cb2, out, widx, nflag, flags);
  k_refine<<<dim3(256), 256, 0, stream>>>(Z, CB, cb2, xxZ, flags, nflag, refmin);
  k_refidx<<<dim3(64), 256, 0, stream>>>(flags, nflag, refmin, widx, out);
  k_zqloss<<<dim3(4096), 256, 0, stream>>>(Z, CB, widx, out, partial);
  k_loss<<<dim3(1), 256, 0, stream>>>(partial, out);
}